// Round 7
// baseline (2034.554 us; speedup 1.0000x reference)
//
#include <hip/hip_runtime.h>

#define NU 500000
#define NI 200000
#define NN (NU + NI)
#define NE 2000000
#define HD 32
#define DF 256
#define OC 96

typedef float        f4  __attribute__((ext_vector_type(4)));
typedef unsigned int u2  __attribute__((ext_vector_type(2)));
typedef short        s8v __attribute__((ext_vector_type(8)));
typedef unsigned short ushort_t;

__device__ __forceinline__ float lrelu(float v){ return v >= 0.f ? v : 0.01f*v; }

__device__ __forceinline__ unsigned int f2bf(float f){
  unsigned int u = __float_as_uint(f);
  u += 0x7fffu + ((u >> 16) & 1u);
  return u >> 16;
}
__device__ __forceinline__ float bflo(unsigned int u){ return __uint_as_float(u << 16); }
__device__ __forceinline__ float bfhi(unsigned int u){ return __uint_as_float(u & 0xffff0000u); }

__device__ __forceinline__ s8v pack8(f4 a, f4 b){
  s8v r;
  r[0]=(short)f2bf(a.x); r[1]=(short)f2bf(a.y); r[2]=(short)f2bf(a.z); r[3]=(short)f2bf(a.w);
  r[4]=(short)f2bf(b.x); r[5]=(short)f2bf(b.y); r[6]=(short)f2bf(b.z); r[7]=(short)f2bf(b.w);
  return r;
}

__global__ void k_zero_i32(int* __restrict__ p, int n){
  int i = blockIdx.x*blockDim.x + threadIdx.x;
  if (i < n) p[i] = 0;
}

// degree histogram (users 0..NU-1, items NU..NN-1)
__global__ void k_deg(const int* __restrict__ esrc, const int* __restrict__ edst,
                      int* __restrict__ cnt){
  int e = blockIdx.x*blockDim.x + threadIdx.x;
  if (e >= NE) return;
  int u = __builtin_nontemporal_load(esrc + e);
  int p = __builtin_nontemporal_load(edst + e);
  atomicAdd(cnt + u, 1);
  atomicAdd(cnt + NU + p, 1);
}

// ---- exclusive scan cnt[NN] -> off[NN] ----
__global__ void k_scan1(const int* __restrict__ cnt, int* __restrict__ off,
                        int* __restrict__ part, int n){
  __shared__ int s[256];
  int t = threadIdx.x, i = blockIdx.x*256 + t;
  int v = (i < n) ? cnt[i] : 0;
  s[t] = v; __syncthreads();
  for (int o = 1; o < 256; o <<= 1) {
    int x = (t >= o) ? s[t-o] : 0;
    __syncthreads(); s[t] += x; __syncthreads();
  }
  if (i < n) off[i] = s[t] - v;
  if (t == 255) part[blockIdx.x] = s[255];
}

__global__ void k_scan2(int* __restrict__ part, int nb){
  __shared__ int s[256];
  __shared__ int carry;
  int t = threadIdx.x;
  if (t == 0) carry = 0;
  __syncthreads();
  for (int c0 = 0; c0 < nb; c0 += 256) {
    int i = c0 + t;
    int v = (i < nb) ? part[i] : 0;
    s[t] = v; __syncthreads();
    for (int o = 1; o < 256; o <<= 1) {
      int x = (t >= o) ? s[t-o] : 0;
      __syncthreads(); s[t] += x; __syncthreads();
    }
    int total = s[255];
    if (i < nb) part[i] = carry + s[t] - v;
    __syncthreads();
    if (t == 0) carry += total;
    __syncthreads();
  }
}

__global__ void k_scan3(int* __restrict__ off, const int* __restrict__ part, int n){
  int i = blockIdx.x*256 + threadIdx.x;
  if (i < n) off[i] += part[blockIdx.x];
}

// scatter edges -> partner slots (user slot [0,NE), item slot [NE,2NE))
__global__ void k_scatter(const int* __restrict__ esrc, const int* __restrict__ edst,
                          const int* __restrict__ off, int* __restrict__ cur,
                          int* __restrict__ partner){
  int e = blockIdx.x*blockDim.x + threadIdx.x;
  if (e >= NE) return;
  int u = __builtin_nontemporal_load(esrc + e);
  int p = __builtin_nontemporal_load(edst + e);
  int s1 = off[u]      + atomicAdd(cur + u,      1);
  int s2 = off[NU + p] + atomicAdd(cur + NU + p, 1);
  partner[s1] = s2;
  partner[s2] = s1;
}

// init user rows + bf16 table + scatter xu to item-side edge slots (fused mat#1)
__global__ void k_init_user_mat(const int* __restrict__ ids, const float* __restrict__ emb,
                                float* __restrict__ outu, ushort_t* __restrict__ tbl,
                                const int* __restrict__ off, const int* __restrict__ cnt,
                                const int* __restrict__ partner,
                                ushort_t* __restrict__ edgeval){
  int tid = blockIdx.x*256 + threadIdx.x;
  int node = tid >> 3;
  if (node >= NU) return;
  int q = tid & 7;
  int uid = ids[node];
  f4 v = *((const f4*)(emb + (size_t)uid*HD) + q);
  *((f4*)(outu + (size_t)node*OC) + q) = v;
  u2 pv; pv.x = f2bf(v.x) | (f2bf(v.y) << 16); pv.y = f2bf(v.z) | (f2bf(v.w) << 16);
  ((u2*)tbl)[(size_t)node*8 + q] = pv;
  int deg = cnt[node];
  if (deg <= 0) return;
  int start = off[node];
  u2* ev = (u2*)edgeval + q;
  int j = 0;
  for (; j + 4 <= deg; j += 4) {
    int s0 = __builtin_nontemporal_load(partner + start + j + 0) - NE;
    int s1 = __builtin_nontemporal_load(partner + start + j + 1) - NE;
    int s2 = __builtin_nontemporal_load(partner + start + j + 2) - NE;
    int s3 = __builtin_nontemporal_load(partner + start + j + 3) - NE;
    ev[(size_t)s0*8] = pv; ev[(size_t)s1*8] = pv;
    ev[(size_t)s2*8] = pv; ev[(size_t)s3*8] = pv;
  }
  for (; j < deg; ++j) {
    int s = __builtin_nontemporal_load(partner + start + j) - NE;
    ev[(size_t)s*8] = pv;
  }
}

// MFMA thin GEMM: outi[:,0:32] = feat @ W^T + b + iemb[ids]
// 1 wave = 16 rows; A = feat rows (bf16-packed in reg), B = W^T fragments.
__global__ __launch_bounds__(256) void k_init_item_mfma(
    const int* __restrict__ ids, const float* __restrict__ emb,
    const float* __restrict__ feat, const float* __restrict__ W,
    const float* __restrict__ bias, float* __restrict__ outi){
  int wave = threadIdx.x >> 6;
  int lane = threadIdx.x & 63;
  int tile = blockIdx.x*4 + wave;
  int row0 = tile*16;
  if (row0 >= NI) return;
  int m = lane & 15, grp = lane >> 4;

  // B fragments: B[k][n] = W[n][k]; lane holds n=m, k=ks*32+grp*8+j
  s8v bfrag[16];
  #pragma unroll
  for (int ks = 0; ks < 8; ++ks) {
    #pragma unroll
    for (int nh = 0; nh < 2; ++nh) {
      const float* wp = W + (size_t)(nh*16 + m)*DF + ks*32 + grp*8;
      f4 w0 = *(const f4*)wp;
      f4 w1 = *(const f4*)(wp + 4);
      bfrag[ks*2 + nh] = pack8(w0, w1);
    }
  }

  f4 acc0 = {0,0,0,0}, acc1 = {0,0,0,0};
  const float* fr = feat + (size_t)(row0 + m)*DF + grp*8;
  #pragma unroll
  for (int ks = 0; ks < 8; ++ks) {
    f4 a0 = *(const f4*)(fr + ks*32);
    f4 a1 = *(const f4*)(fr + ks*32 + 4);
    s8v af = pack8(a0, a1);
    acc0 = __builtin_amdgcn_mfma_f32_16x16x32_bf16(af, bfrag[ks*2+0], acc0, 0, 0, 0);
    acc1 = __builtin_amdgcn_mfma_f32_16x16x32_bf16(af, bfrag[ks*2+1], acc1, 0, 0, 0);
  }

  // D: row = grp*4+j, col h = m (acc0) / 16+m (acc1)
  #pragma unroll
  for (int j = 0; j < 4; ++j) {
    int r = row0 + grp*4 + j;
    int pid = ids[r];
    float v0 = acc0[j] + emb[(size_t)pid*HD + m]      + bias[m];
    float v1 = acc1[j] + emb[(size_t)pid*HD + 16 + m] + bias[16 + m];
    outi[(size_t)r*OC + m]      = v0;
    outi[(size_t)r*OC + 16 + m] = v1;
  }
}

// mat from strided f32 rows (src col scol) -> edgeval[partner slots]
__global__ void k_mat_f32(const float* __restrict__ srcbase, int scol, int n_src, int nodebase,
                          const int* __restrict__ off, const int* __restrict__ cnt,
                          const int* __restrict__ partner, ushort_t* __restrict__ edgeval,
                          int slotbase){
  int tid = blockIdx.x*256 + threadIdx.x;
  int node = tid >> 3;
  if (node >= n_src) return;
  int q = tid & 7;
  int gnode = nodebase + node;
  int deg = cnt[gnode];
  if (deg <= 0) return;
  int start = off[gnode];
  f4 v = *((const f4*)(srcbase + (size_t)node*OC + scol) + q);
  u2 pv; pv.x = f2bf(v.x) | (f2bf(v.y) << 16); pv.y = f2bf(v.z) | (f2bf(v.w) << 16);
  u2* ev = (u2*)edgeval + q;
  int j = 0;
  for (; j + 4 <= deg; j += 4) {
    int s0 = __builtin_nontemporal_load(partner + start + j + 0) - slotbase;
    int s1 = __builtin_nontemporal_load(partner + start + j + 1) - slotbase;
    int s2 = __builtin_nontemporal_load(partner + start + j + 2) - slotbase;
    int s3 = __builtin_nontemporal_load(partner + start + j + 3) - slotbase;
    ev[(size_t)s0*8] = pv; ev[(size_t)s1*8] = pv;
    ev[(size_t)s2*8] = pv; ev[(size_t)s3*8] = pv;
  }
  for (; j < deg; ++j) {
    int s = __builtin_nontemporal_load(partner + start + j) - slotbase;
    ev[(size_t)s*8] = pv;
  }
}

// mat from dense bf16 table -> edgeval[partner slots]
__global__ void k_mat_tbl(const ushort_t* __restrict__ tbl, int n_src, int nodebase,
                          const int* __restrict__ off, const int* __restrict__ cnt,
                          const int* __restrict__ partner, ushort_t* __restrict__ edgeval,
                          int slotbase){
  int tid = blockIdx.x*256 + threadIdx.x;
  int node = tid >> 3;
  if (node >= n_src) return;
  int q = tid & 7;
  int gnode = nodebase + node;
  int deg = cnt[gnode];
  if (deg <= 0) return;
  int start = off[gnode];
  u2 pv = ((const u2*)tbl)[(size_t)node*8 + q];
  u2* ev = (u2*)edgeval + q;
  int j = 0;
  for (; j + 4 <= deg; j += 4) {
    int s0 = __builtin_nontemporal_load(partner + start + j + 0) - slotbase;
    int s1 = __builtin_nontemporal_load(partner + start + j + 1) - slotbase;
    int s2 = __builtin_nontemporal_load(partner + start + j + 2) - slotbase;
    int s3 = __builtin_nontemporal_load(partner + start + j + 3) - slotbase;
    ev[(size_t)s0*8] = pv; ev[(size_t)s1*8] = pv;
    ev[(size_t)s2*8] = pv; ev[(size_t)s3*8] = pv;
  }
  for (; j < deg; ++j) {
    int s = __builtin_nontemporal_load(partner + start + j) - slotbase;
    ev[(size_t)s*8] = pv;
  }
}

// fused: segmented mean over edgeval + SAGE linear + leakyReLU via LDS staging.
// block = 32 nodes x 8 lanes; matvec reads mean/x from padded LDS (conflict-free).
__global__ __launch_bounds__(256) void k_aggfin2(
    float* __restrict__ dstbase, int n, int nodebase,
    const ushort_t* __restrict__ edgeval, int slotbase,
    int xoff, int outoff,
    const int* __restrict__ off, const int* __restrict__ cnt,
    const float* __restrict__ Wl, const float* __restrict__ bl,
    const float* __restrict__ Wr, ushort_t* __restrict__ tblout){
  __shared__ float mbuf[32*36];
  __shared__ float xbuf[32*36];
  int t = threadIdx.x;
  int nl = t >> 3;
  int q = t & 7;
  int node = blockIdx.x*32 + nl;
  bool valid = node < n;
  f4 a0 = {0,0,0,0}, a1 = a0, a2 = a0, a3 = a0, xv = a0;
  int deg = 0;
  if (valid) {
    int g = nodebase + node;
    deg = cnt[g];
    int start = off[g] - slotbase;
    xv = *((const f4*)(dstbase + (size_t)node*OC + xoff) + q);
    const u2* ev = (const u2*)edgeval + q;
    int j = 0;
    for (; j + 4 <= deg; j += 4) {
      u2 r0 = ev[(size_t)(start+j+0)*8];
      u2 r1 = ev[(size_t)(start+j+1)*8];
      u2 r2 = ev[(size_t)(start+j+2)*8];
      u2 r3 = ev[(size_t)(start+j+3)*8];
      a0.x += bflo(r0.x); a0.y += bfhi(r0.x); a0.z += bflo(r0.y); a0.w += bfhi(r0.y);
      a1.x += bflo(r1.x); a1.y += bfhi(r1.x); a1.z += bflo(r1.y); a1.w += bfhi(r1.y);
      a2.x += bflo(r2.x); a2.y += bfhi(r2.x); a2.z += bflo(r2.y); a2.w += bfhi(r2.y);
      a3.x += bflo(r3.x); a3.y += bfhi(r3.x); a3.z += bflo(r3.y); a3.w += bfhi(r3.y);
    }
    for (; j < deg; ++j) {
      u2 r = ev[(size_t)(start+j)*8];
      a0.x += bflo(r.x); a0.y += bfhi(r.x); a0.z += bflo(r.y); a0.w += bfhi(r.y);
    }
    a0 += a1 + a2 + a3;
  }
  float inv = (deg > 0) ? 1.f/(float)deg : 0.f;
  f4 mv; mv.x = a0.x*inv; mv.y = a0.y*inv; mv.z = a0.z*inv; mv.w = a0.w*inv;
  *(f4*)(mbuf + nl*36 + q*4) = mv;
  *(f4*)(xbuf + nl*36 + q*4) = xv;
  __syncthreads();
  if (!valid) return;
  const f4* mr = (const f4*)(mbuf + nl*36);
  const f4* xr = (const f4*)(xbuf + nl*36);
  float y[4];
  #pragma unroll
  for (int k = 0; k < 4; ++k) {
    int h = q*4 + k;
    float s = bl[h];
    const f4* wl = (const f4*)(Wl + h*HD);
    const f4* wr = (const f4*)(Wr + h*HD);
    #pragma unroll
    for (int j4 = 0; j4 < 8; ++j4) {
      f4 mm = mr[j4], wv = wl[j4];
      s += mm.x*wv.x + mm.y*wv.y + mm.z*wv.z + mm.w*wv.w;
    }
    #pragma unroll
    for (int j4 = 0; j4 < 8; ++j4) {
      f4 xx = xr[j4], wv = wr[j4];
      s += xx.x*wv.x + xx.y*wv.y + xx.z*wv.z + xx.w*wv.w;
    }
    y[k] = lrelu(s);
  }
  f4 yo; yo.x = y[0]; yo.y = y[1]; yo.z = y[2]; yo.w = y[3];
  *((f4*)(dstbase + (size_t)node*OC + outoff) + q) = yo;
  if (tblout) {
    u2 pv;
    pv.x = f2bf(y[0]) | (f2bf(y[1]) << 16);
    pv.y = f2bf(y[2]) | (f2bf(y[3]) << 16);
    ((u2*)tblout)[(size_t)node*8 + q] = pv;
  }
}

extern "C" void kernel_launch(void* const* d_in, const int* in_sizes, int n_in,
                              void* d_out, int out_size, void* d_ws, size_t ws_size,
                              hipStream_t stream) {
  const int*   user_ids = (const int*)d_in[0];
  const int*   prod_ids = (const int*)d_in[1];
  const float* feat     = (const float*)d_in[2];
  const int*   er       = (const int*)d_in[3];
  const float* uemb     = (const float*)d_in[5];
  const float* iemb     = (const float*)d_in[6];
  const float* fW       = (const float*)d_in[7];
  const float* fb       = (const float*)d_in[8];
  const float* Wl_up1 = (const float*)d_in[9];
  const float* bl_up1 = (const float*)d_in[10];
  const float* Wr_up1 = (const float*)d_in[11];
  const float* Wl_pu1 = (const float*)d_in[12];
  const float* bl_pu1 = (const float*)d_in[13];
  const float* Wr_pu1 = (const float*)d_in[14];
  const float* Wl_up2 = (const float*)d_in[15];
  const float* bl_up2 = (const float*)d_in[16];
  const float* Wr_up2 = (const float*)d_in[17];
  const float* Wl_pu2 = (const float*)d_in[18];
  const float* bl_pu2 = (const float*)d_in[19];
  const float* Wr_pu2 = (const float*)d_in[20];

  float* outu = (float*)d_out;
  float* outi = outu + (size_t)NU*OC;

  // ws: ints cnt[NN]|cur[NN]|off[NN]|part[2736]|partner[2NE],
  // then edgeval (NE x 64 B, 256-aligned), then tblA (NU x 64 B bf16)
  int* cnt  = (int*)d_ws;
  int* cur  = cnt + NN;
  int* off  = cur + NN;
  int* part = off + NN;
  int* pn   = part + 2736;
  size_t base_bytes = ((size_t)3*NN + 2736 + 2*(size_t)NE) * 4;
  size_t ev_off = (base_bytes + 255) & ~(size_t)255;
  ushort_t* edgeval = (ushort_t*)((char*)d_ws + ev_off);
  ushort_t* tblA    = (ushort_t*)((char*)d_ws + ev_off + (size_t)NE*64);

  const int* er_src = er;        // users
  const int* er_dst = er + NE;   // items

  const int B = 256;
  const int NB1 = (NN + 255)/256;
  const int GU8 = ((size_t)NU*8 + B - 1)/B, GI8 = ((size_t)NI*8 + B - 1)/B;
  const int GU32 = (NU + 31)/32, GI32 = (NI + 31)/32;

  k_zero_i32<<<(2*NN + B - 1)/B, B, 0, stream>>>(cnt, 2*NN);
  k_deg<<<(NE + B - 1)/B, B, 0, stream>>>(er_src, er_dst, cnt);
  k_scan1<<<NB1, B, 0, stream>>>(cnt, off, part, NN);
  k_scan2<<<1, B, 0, stream>>>(part, NB1);
  k_scan3<<<NB1, B, 0, stream>>>(off, part, NN);
  k_scatter<<<(NE + B - 1)/B, B, 0, stream>>>(er_src, er_dst, off, cur, pn);

  // init users (+ xu table + layer-1 item-side edge scatter, fused)
  k_init_user_mat<<<GU8, B, 0, stream>>>(user_ids, uemb, outu, tblA, off, cnt, pn, edgeval);
  // init items via MFMA
  k_init_item_mfma<<<(NI + 63)/64, 256, 0, stream>>>(prod_ids, iemb, feat, fW, fb, outi);

  // s1a: items <- xu
  k_aggfin2<<<GI32, B, 0, stream>>>(outi, NI, NU, edgeval, NE, 0, 32, off, cnt,
                                    Wl_up1, bl_up1, Wr_up1, (ushort_t*)nullptr);
  // s1b: users <- xp  (mat reads outi col 0)
  k_mat_f32<<<GI8, B, 0, stream>>>(outi, 0, NI, NU, off, cnt, pn, edgeval, 0);
  k_aggfin2<<<GU32, B, 0, stream>>>(outu, NU, 0, edgeval, 0, 0, 32, off, cnt,
                                    Wl_pu1, bl_pu1, Wr_pu1, tblA);   // writes u1 table
  // s2a: items <- u1 (mat reads tblA)
  k_mat_tbl<<<GU8, B, 0, stream>>>(tblA, NU, 0, off, cnt, pn, edgeval, NE);
  k_aggfin2<<<GI32, B, 0, stream>>>(outi, NI, NU, edgeval, NE, 32, 64, off, cnt,
                                    Wl_up2, bl_up2, Wr_up2, (ushort_t*)nullptr);
  // s2b: users <- p1 (mat reads outi col 32)
  k_mat_f32<<<GI8, B, 0, stream>>>(outi, 32, NI, NU, off, cnt, pn, edgeval, 0);
  k_aggfin2<<<GU32, B, 0, stream>>>(outu, NU, 0, edgeval, 0, 32, 64, off, cnt,
                                    Wl_pu2, bl_pu2, Wr_pu2, (ushort_t*)nullptr);
}

// Round 8
// 1943.053 us; speedup vs baseline: 1.0471x; 1.0471x over previous
//
#include <hip/hip_runtime.h>

#define NU 500000
#define NI 200000
#define NN (NU + NI)
#define NE 2000000
#define HD 32
#define DF 256
#define OC 96

typedef float        f4  __attribute__((ext_vector_type(4)));
typedef unsigned int u2  __attribute__((ext_vector_type(2)));
typedef unsigned int u4v __attribute__((ext_vector_type(4)));
typedef short        s8v __attribute__((ext_vector_type(8)));
typedef unsigned short ushort_t;

__device__ __forceinline__ float lrelu(float v){ return v >= 0.f ? v : 0.01f*v; }

__device__ __forceinline__ unsigned int f2bf(float f){
  unsigned int u = __float_as_uint(f);
  u += 0x7fffu + ((u >> 16) & 1u);
  return u >> 16;
}
__device__ __forceinline__ float bflo(unsigned int u){ return __uint_as_float(u << 16); }
__device__ __forceinline__ float bfhi(unsigned int u){ return __uint_as_float(u & 0xffff0000u); }

__device__ __forceinline__ s8v pack8(f4 a, f4 b){
  s8v r;
  r[0]=(short)f2bf(a.x); r[1]=(short)f2bf(a.y); r[2]=(short)f2bf(a.z); r[3]=(short)f2bf(a.w);
  r[4]=(short)f2bf(b.x); r[5]=(short)f2bf(b.y); r[6]=(short)f2bf(b.z); r[7]=(short)f2bf(b.w);
  return r;
}

// degree histogram (users 0..NU-1, items NU..NN-1)
__global__ void k_deg(const int* __restrict__ esrc, const int* __restrict__ edst,
                      int* __restrict__ cnt){
  int e = blockIdx.x*blockDim.x + threadIdx.x;
  if (e >= NE) return;
  int u = __builtin_nontemporal_load(esrc + e);
  int p = __builtin_nontemporal_load(edst + e);
  atomicAdd(cnt + u, 1);
  atomicAdd(cnt + NU + p, 1);
}

// outu[:,0:32] = user_emb[ids]; also dense bf16 table (xu)
__global__ void k_init_user(const int* __restrict__ ids, const float* __restrict__ emb,
                            float* __restrict__ outu, ushort_t* __restrict__ tbl){
  int tid = blockIdx.x*256 + threadIdx.x;
  int node = tid >> 3;
  if (node >= NU) return;
  int q = tid & 7;
  int uid = ids[node];
  f4 v = *((const f4*)(emb + (size_t)uid*HD) + q);
  __builtin_nontemporal_store(v, (f4*)(outu + (size_t)node*OC) + q);
  u2 pv; pv.x = f2bf(v.x) | (f2bf(v.y) << 16); pv.y = f2bf(v.z) | (f2bf(v.w) << 16);
  ((u2*)tbl)[(size_t)node*8 + q] = pv;
}

// MFMA thin GEMM: outi[:,0:32] = feat @ W^T + b + iemb[ids]  (verified round 7)
__global__ __launch_bounds__(256) void k_init_item_mfma(
    const int* __restrict__ ids, const float* __restrict__ emb,
    const float* __restrict__ feat, const float* __restrict__ W,
    const float* __restrict__ bias, float* __restrict__ outi){
  int wave = threadIdx.x >> 6;
  int lane = threadIdx.x & 63;
  int tile = blockIdx.x*4 + wave;
  int row0 = tile*16;
  if (row0 >= NI) return;
  int m = lane & 15, grp = lane >> 4;

  s8v bfrag[16];
  #pragma unroll
  for (int ks = 0; ks < 8; ++ks) {
    #pragma unroll
    for (int nh = 0; nh < 2; ++nh) {
      const float* wp = W + (size_t)(nh*16 + m)*DF + ks*32 + grp*8;
      f4 w0 = *(const f4*)wp;
      f4 w1 = *(const f4*)(wp + 4);
      bfrag[ks*2 + nh] = pack8(w0, w1);
    }
  }

  f4 acc0 = {0,0,0,0}, acc1 = {0,0,0,0};
  const float* fr = feat + (size_t)(row0 + m)*DF + grp*8;
  #pragma unroll
  for (int ks = 0; ks < 8; ++ks) {
    f4 a0 = *(const f4*)(fr + ks*32);
    f4 a1 = *(const f4*)(fr + ks*32 + 4);
    s8v af = pack8(a0, a1);
    acc0 = __builtin_amdgcn_mfma_f32_16x16x32_bf16(af, bfrag[ks*2+0], acc0, 0, 0, 0);
    acc1 = __builtin_amdgcn_mfma_f32_16x16x32_bf16(af, bfrag[ks*2+1], acc1, 0, 0, 0);
  }

  #pragma unroll
  for (int j = 0; j < 4; ++j) {
    int r = row0 + grp*4 + j;
    int pid = ids[r];
    float v0 = acc0[j] + emb[(size_t)pid*HD + m]      + bias[m];
    float v1 = acc1[j] + emb[(size_t)pid*HD + 16 + m] + bias[16 + m];
    outi[(size_t)r*OC + m]      = v0;
    outi[(size_t)r*OC + 16 + m] = v1;
  }
}

// dense bf16 table (xp) from outi col 0
__global__ void k_tbl_item(const float* __restrict__ outi, ushort_t* __restrict__ tbl){
  int tid = blockIdx.x*256 + threadIdx.x;
  int node = tid >> 3;
  if (node >= NI) return;
  int q = tid & 7;
  f4 v = *((const f4*)(outi + (size_t)node*OC) + q);
  u2 pv; pv.x = f2bf(v.x) | (f2bf(v.y) << 16); pv.y = f2bf(v.z) | (f2bf(v.w) << 16);
  ((u2*)tbl)[(size_t)node*8 + q] = pv;
}

// edge-parallel push: 8 lanes/edge, read src row from bf16 table (L2/L3-resident),
// accumulate into dense bf16 acc via packed bf16 atomics. No loops, max TLP.
__global__ void k_push(const ushort_t* __restrict__ tbl,
                       const int* __restrict__ eS, const int* __restrict__ eD,
                       ushort_t* __restrict__ acc){
  int tid = blockIdx.x*256 + threadIdx.x;
  int e = tid >> 3;
  if (e >= NE) return;
  int q = tid & 7;
  int s = __builtin_nontemporal_load(eS + e);
  int d = __builtin_nontemporal_load(eD + e);
  u2 v = ((const u2*)tbl)[(size_t)s*8 + q];
  ushort_t* a = acc + (size_t)d*HD + q*4;
  asm volatile("global_atomic_pk_add_bf16 %0, %1, off"          :: "v"(a), "v"(v.x) : "memory");
  asm volatile("global_atomic_pk_add_bf16 %0, %1, off offset:4" :: "v"(a), "v"(v.y) : "memory");
}

// thread-per-node: mean = acc/deg (bf16->f32), x from bf16 table,
// y = lrelu(Wl*mean + bl + Wr*x); write out col + optional next table.
__global__ void k_fin3(float* __restrict__ dstbase, int n,
                       const ushort_t* __restrict__ acc, const int* __restrict__ cnt,
                       const ushort_t* __restrict__ xtbl, int outoff,
                       const float* __restrict__ Wl, const float* __restrict__ bl,
                       const float* __restrict__ Wr, ushort_t* __restrict__ tblout){
  int i = blockIdx.x*blockDim.x + threadIdx.x;
  if (i >= n) return;
  int c = cnt[i];
  float inv = (c > 0) ? 1.f/(float)c : 0.f;
  float m[HD], x[HD];
  const u4v* ar = (const u4v*)(acc + (size_t)i*HD);
  const u4v* xr = (const u4v*)(xtbl + (size_t)i*HD);
  #pragma unroll
  for (int t = 0; t < 4; ++t) {
    u4v v = ar[t];
    m[8*t+0] = bflo(v.x)*inv; m[8*t+1] = bfhi(v.x)*inv;
    m[8*t+2] = bflo(v.y)*inv; m[8*t+3] = bfhi(v.y)*inv;
    m[8*t+4] = bflo(v.z)*inv; m[8*t+5] = bfhi(v.z)*inv;
    m[8*t+6] = bflo(v.w)*inv; m[8*t+7] = bfhi(v.w)*inv;
    u4v xv = xr[t];
    x[8*t+0] = bflo(xv.x); x[8*t+1] = bfhi(xv.x);
    x[8*t+2] = bflo(xv.y); x[8*t+3] = bfhi(xv.y);
    x[8*t+4] = bflo(xv.z); x[8*t+5] = bfhi(xv.z);
    x[8*t+6] = bflo(xv.w); x[8*t+7] = bfhi(xv.w);
  }
  float y[HD];
  #pragma unroll
  for (int h = 0; h < HD; ++h) {
    float s = bl[h];
    #pragma unroll
    for (int j = 0; j < HD; ++j) s += m[j]*Wl[h*HD+j];   // W uniform -> s_load
    #pragma unroll
    for (int j = 0; j < HD; ++j) s += x[j]*Wr[h*HD+j];
    y[h] = lrelu(s);
  }
  float* row = dstbase + (size_t)i*OC + outoff;
  #pragma unroll
  for (int qq = 0; qq < 8; ++qq) {
    f4 yo; yo.x=y[4*qq+0]; yo.y=y[4*qq+1]; yo.z=y[4*qq+2]; yo.w=y[4*qq+3];
    __builtin_nontemporal_store(yo, (f4*)row + qq);
  }
  if (tblout) {
    u4v pv[4];
    #pragma unroll
    for (int t = 0; t < 4; ++t) {
      pv[t].x = f2bf(y[8*t+0]) | (f2bf(y[8*t+1]) << 16);
      pv[t].y = f2bf(y[8*t+2]) | (f2bf(y[8*t+3]) << 16);
      pv[t].z = f2bf(y[8*t+4]) | (f2bf(y[8*t+5]) << 16);
      pv[t].w = f2bf(y[8*t+6]) | (f2bf(y[8*t+7]) << 16);
    }
    u4v* tb = (u4v*)(tblout + (size_t)i*HD);
    #pragma unroll
    for (int t = 0; t < 4; ++t) tb[t] = pv[t];
  }
}

extern "C" void kernel_launch(void* const* d_in, const int* in_sizes, int n_in,
                              void* d_out, int out_size, void* d_ws, size_t ws_size,
                              hipStream_t stream) {
  const int*   user_ids = (const int*)d_in[0];
  const int*   prod_ids = (const int*)d_in[1];
  const float* feat     = (const float*)d_in[2];
  const int*   er       = (const int*)d_in[3];   // [2, NE]: row0 = user, row1 = item
  const float* uemb     = (const float*)d_in[5];
  const float* iemb     = (const float*)d_in[6];
  const float* fW       = (const float*)d_in[7];
  const float* fb       = (const float*)d_in[8];
  const float* Wl_up1 = (const float*)d_in[9];
  const float* bl_up1 = (const float*)d_in[10];
  const float* Wr_up1 = (const float*)d_in[11];
  const float* Wl_pu1 = (const float*)d_in[12];
  const float* bl_pu1 = (const float*)d_in[13];
  const float* Wr_pu1 = (const float*)d_in[14];
  const float* Wl_up2 = (const float*)d_in[15];
  const float* bl_up2 = (const float*)d_in[16];
  const float* Wr_up2 = (const float*)d_in[17];
  const float* Wl_pu2 = (const float*)d_in[18];
  const float* bl_pu2 = (const float*)d_in[19];
  const float* Wr_pu2 = (const float*)d_in[20];

  float* outu = (float*)d_out;
  float* outi = outu + (size_t)NU*OC;

  // ws: cnt[NN] i32 | tblU | tblI | tblU2 | tblI2 | accU | accI  (bf16 rows of 64 B)
  char* w = (char*)d_ws;
  int* cnt = (int*)w;                         w += ((size_t)NN*4 + 255) & ~(size_t)255;
  ushort_t* tblU  = (ushort_t*)w;             w += (size_t)NU*HD*2;
  ushort_t* tblI  = (ushort_t*)w;             w += (size_t)NI*HD*2;
  ushort_t* tblU2 = (ushort_t*)w;             w += (size_t)NU*HD*2;
  ushort_t* tblI2 = (ushort_t*)w;             w += (size_t)NI*HD*2;
  ushort_t* accU  = (ushort_t*)w;             w += (size_t)NU*HD*2;
  ushort_t* accI  = (ushort_t*)w;

  const int* er_src = er;        // users
  const int* er_dst = er + NE;   // items

  const int B = 256;
  const int GE  = (NE + B - 1)/B;
  const int GE8 = ((size_t)NE*8 + B - 1)/B;
  const int GU8 = ((size_t)NU*8 + B - 1)/B, GI8 = ((size_t)NI*8 + B - 1)/B;
  const int GU1 = (NU + B - 1)/B,           GI1 = (NI + B - 1)/B;
  const size_t accU_bytes = (size_t)NU*HD*2, accI_bytes = (size_t)NI*HD*2;

  hipMemsetAsync(cnt, 0, (size_t)NN*4, stream);
  k_deg<<<GE, B, 0, stream>>>(er_src, er_dst, cnt);

  k_init_user<<<GU8, B, 0, stream>>>(user_ids, uemb, outu, tblU);
  k_init_item_mfma<<<(NI + 63)/64, 256, 0, stream>>>(prod_ids, iemb, feat, fW, fb, outi);
  k_tbl_item<<<GI8, B, 0, stream>>>(outi, tblI);

  // s1a: items <- users (xu)
  hipMemsetAsync(accI, 0, accI_bytes, stream);
  k_push<<<GE8, B, 0, stream>>>(tblU, er_src, er_dst, accI);
  k_fin3<<<GI1, B, 0, stream>>>(outi, NI, accI, cnt + NU, tblI, 32,
                                Wl_up1, bl_up1, Wr_up1, tblI2);
  // s1b: users <- items (xp)
  hipMemsetAsync(accU, 0, accU_bytes, stream);
  k_push<<<GE8, B, 0, stream>>>(tblI, er_dst, er_src, accU);
  k_fin3<<<GU1, B, 0, stream>>>(outu, NU, accU, cnt, tblU, 32,
                                Wl_pu1, bl_pu1, Wr_pu1, tblU2);
  // s2a: items <- u1
  hipMemsetAsync(accI, 0, accI_bytes, stream);
  k_push<<<GE8, B, 0, stream>>>(tblU2, er_src, er_dst, accI);
  k_fin3<<<GI1, B, 0, stream>>>(outi, NI, accI, cnt + NU, tblI2, 64,
                                Wl_up2, bl_up2, Wr_up2, (ushort_t*)nullptr);
  // s2b: users <- p1
  hipMemsetAsync(accU, 0, accU_bytes, stream);
  k_push<<<GE8, B, 0, stream>>>(tblI2, er_dst, er_src, accU);
  k_fin3<<<GU1, B, 0, stream>>>(outu, NU, accU, cnt, tblU2, 64,
                                Wl_pu2, bl_pu2, Wr_pu2, (ushort_t*)nullptr);
}